// Round 2
// baseline (243.506 us; speedup 1.0000x reference)
//
#include <hip/hip_runtime.h>
#include <hip/hip_bf16.h>
#include <stdint.h>

#define B_  64
#define N_  576
#define D_  1024
#define K_  144
#define HW_ 24
#define DIST_THR_F 16.733200530681511f

using bf16x8 = __attribute__((ext_vector_type(8))) short;
using f32x4  = __attribute__((ext_vector_type(4))) float;

__device__ __forceinline__ unsigned short f2bf(float f) {
    unsigned u = __float_as_uint(f);
    u += 0x7fffu + ((u >> 16) & 1u);
    return (unsigned short)(u >> 16);
}

// ---------------- Kernel 1: row L2-normalize hs_sim and cast to bf16 ----------------
__global__ __launch_bounds__(256) void k_normcast(const float* __restrict__ x,
                                                  unsigned short* __restrict__ pn) {
    int row  = blockIdx.x * 4 + (threadIdx.x >> 6);
    int lane = threadIdx.x & 63;
    const float4* src = reinterpret_cast<const float4*>(x + (size_t)row * D_);
    float4 v[4];
    float ss = 0.f;
#pragma unroll
    for (int q = 0; q < 4; q++) {
        v[q] = src[lane + 64 * q];
        ss += v[q].x * v[q].x + v[q].y * v[q].y + v[q].z * v[q].z + v[q].w * v[q].w;
    }
#pragma unroll
    for (int m = 32; m >= 1; m >>= 1) ss += __shfl_xor(ss, m, 64);
    float inv = 1.0f / fmaxf(sqrtf(ss), 1e-12f);
    ushort4* dst = reinterpret_cast<ushort4*>(pn + (size_t)row * D_);
#pragma unroll
    for (int q = 0; q < 4; q++) {
        ushort4 o;
        o.x = f2bf(v[q].x * inv); o.y = f2bf(v[q].y * inv);
        o.z = f2bf(v[q].z * inv); o.w = f2bf(v[q].w * inv);
        dst[lane + 64 * q] = o;
    }
}

// ---------------- Kernel 2: token selection (one block per batch) ----------------
__global__ __launch_bounds__(256) void k_select(const float* __restrict__ metric,
                                                int* __restrict__ bench_idx,
                                                int* __restrict__ high,
                                                float* __restrict__ out_idx) {
    __shared__ float sm[N_];
    __shared__ float sc[512];
    __shared__ int   si[512];
    __shared__ unsigned smask[18];
    __shared__ int   wpref[18];
    __shared__ float thr_s;
    int b = blockIdx.x, tid = threadIdx.x;
    for (int i = tid; i < N_; i += 256) sm[i] = metric[b * N_ + i];
    if (tid < 18) smask[tid] = 0u;
    __syncthreads();
    if (tid < 144) {
        int ry = tid / 12, rx = tid - ry * 12;
        int base = ry * 48 + rx * 2;
        float vv[4] = { sm[base], sm[base + 1], sm[base + 24], sm[base + 25] };
        int   tk[4] = { base, base + 1, base + 24, base + 25 };
        int a0 = 0;
#pragma unroll
        for (int j = 1; j < 4; j++) if (vv[j] > vv[a0]) a0 = j;
        int a1 = -1;
#pragma unroll
        for (int j = 0; j < 4; j++) {
            if (j == a0) continue;
            if (a1 < 0 || vv[j] > vv[a1]) a1 = j;
        }
        sc[2 * tid]     = vv[a0]; si[2 * tid]     = tk[a0];
        sc[2 * tid + 1] = vv[a1]; si[2 * tid + 1] = tk[a1];
    }
    for (int i = 288 + tid; i < 512; i += 256) { sc[i] = -1e30f; si[i] = 0x7fffffff; }
    __syncthreads();
    for (int k = 2; k <= 512; k <<= 1) {
        for (int j = k >> 1; j > 0; j >>= 1) {
#pragma unroll 2
            for (int t = tid; t < 512; t += 256) {
                int ixj = t ^ j;
                if (ixj > t) {
                    float s1 = sc[t], s2 = sc[ixj];
                    int   i1 = si[t], i2 = si[ixj];
                    bool before = (s1 > s2) || (s1 == s2 && i1 < i2);
                    bool up = ((t & k) == 0);
                    if (up ? !before : before) {
                        sc[t] = s2; sc[ixj] = s1; si[t] = i2; si[ixj] = i1;
                    }
                }
            }
            __syncthreads();
        }
    }
    if (tid == 0) {
        float qpos = 0.55f * 143.0f;
        float g = qpos - 78.0f;
        thr_s = sc[65] * (1.0f - g) + sc[64] * g;
    }
    if (tid < 144) atomicOr(&smask[si[tid] >> 5], 1u << (si[tid] & 31));
    __syncthreads();
    if (tid == 0) {
        int acc = 0;
        for (int w = 0; w < 18; w++) { wpref[w] = acc; acc += __popc(smask[w]); }
    }
    __syncthreads();
    if (tid < 144) {
        int tok = si[tid], w = tok >> 5;
        int rank = wpref[w] + __popc(smask[w] & ((1u << (tok & 31)) - 1u));
        bench_idx[b * K_ + rank] = tok;
        high[b * K_ + rank] = (sc[tid] >= thr_s) ? 1 : 0;
        out_idx[b * K_ + rank] = (float)tok;
    }
}

// ---------------- Kernel 3: sim GEMM + relu*penalty + row-normalize -> bwn (bf16) ------
// block = (b, rt): rows rt*16..+15, all 576 cols. 4 waves; wave w -> cols w*144..+143.
__global__ __launch_bounds__(256) void k_sim2(const unsigned short* __restrict__ pn,
                                              const int* __restrict__ bench_idx,
                                              const int* __restrict__ high,
                                              unsigned short* __restrict__ bwn) {
    __shared__ float ls[4][16];
    // XCD swizzle: 576 blocks = 8 xcd * 72 slots; batch b pinned to xcd b%8
    int bid  = blockIdx.x;
    int xcd  = bid & 7;
    int slot = bid >> 3;           // 0..71
    int b    = xcd + 8 * (slot / 9);
    int rt   = slot % 9;
    int w    = threadIdx.x >> 6;   // wave 0..3
    int lane = threadIdx.x & 63;
    int g = lane >> 4, r16 = lane & 15;

    const unsigned short* pnb = pn + (size_t)b * N_ * D_;
    int tokA = bench_idx[b * K_ + rt * 16 + r16];
    const unsigned short* aptr = pnb + (size_t)tokA * D_;

    f32x4 acc[9] = {};
    for (int kk = 0; kk < D_; kk += 32) {
        bf16x8 a = *reinterpret_cast<const bf16x8*>(aptr + kk + g * 8);
        bf16x8 bfr[9];
#pragma unroll
        for (int nj = 0; nj < 9; nj++)
            bfr[nj] = *reinterpret_cast<const bf16x8*>(pnb + (size_t)(w * 144 + nj * 16 + r16) * D_ + kk + g * 8);
#pragma unroll
        for (int nj = 0; nj < 9; nj++)
            acc[nj] = __builtin_amdgcn_mfma_f32_16x16x32_bf16(a, bfr[nj], acc[nj], 0, 0, 0);
    }

    // epilogue: row i = rt*16 + g*4 + r, col = w*144 + nj*16 + r16
    int   ti[4], hi[4];
    float val[4][9];
    float partial[4];
#pragma unroll
    for (int r = 0; r < 4; r++) {
        int i = rt * 16 + g * 4 + r;
        ti[r] = bench_idx[b * K_ + i];
        hi[r] = high[b * K_ + i];
        int y1 = ti[r] / HW_, x1 = ti[r] % HW_;
        float s = 0.f;
#pragma unroll
        for (int nj = 0; nj < 9; nj++) {
            int col = w * 144 + nj * 16 + r16;
            int y2 = col / HW_, x2 = col % HW_;
            float dy = (float)(y1 - y2), dx = (float)(x1 - x2);
            float dist = sqrtf(dy * dy + dx * dx);
            float pen = 1.0f - fminf(dist / DIST_THR_F, 1.0f);
            float v = fmaxf(acc[nj][r], 0.0f) * pen;
            val[r][nj] = v;
            s += v;
        }
        partial[r] = s;
    }
#pragma unroll
    for (int m = 1; m <= 8; m <<= 1)
#pragma unroll
        for (int r = 0; r < 4; r++) partial[r] += __shfl_xor(partial[r], m, 64);
    if (r16 == 0) {
#pragma unroll
        for (int r = 0; r < 4; r++) ls[w][g * 4 + r] = partial[r];
    }
    __syncthreads();
#pragma unroll
    for (int r = 0; r < 4; r++) {
        int i = rt * 16 + g * 4 + r;
        float tot = ls[0][g * 4 + r] + ls[1][g * 4 + r] + ls[2][g * 4 + r] + ls[3][g * 4 + r] + 1e-8f;
        float scale = 1.0f / tot;
        unsigned short* prow = bwn + (size_t)(b * K_ + i) * N_;
#pragma unroll
        for (int nj = 0; nj < 9; nj++) {
            int col = w * 144 + nj * 16 + r16;
            unsigned short o;
            if (col == ti[r])      o = (unsigned short)0x3F80;     // self = 1.0
            else if (hi[r])        o = (unsigned short)0;          // high row -> one-hot
            else                   o = f2bf(val[r][nj] * scale);
            prow[col] = o;
        }
    }
}

// ---------------- Kernel 4: aggregation GEMM with fused transpose+cast of agg ----------
// block = (b, dt): out rows 0..143, d cols dt*32..+31. 192 threads (3 waves).
// LDS holds agg panel transposed: lds[d(32)][j(576)] bf16, row stride 584 u16
// (292 dwords == 4 mod 32 -> conflict-free ds_read_b128 fragments).
__global__ __launch_bounds__(192) void k_agg2(const unsigned short* __restrict__ bwn,
                                              const float* __restrict__ agg,
                                              float* __restrict__ out) {
    __shared__ unsigned short lds[32][584];
    // XCD swizzle: 2048 blocks = 8 xcd * 256 slots; batch b pinned to xcd b%8
    int bid  = blockIdx.x;
    int xcd  = bid & 7;
    int slot = bid >> 3;             // 0..255
    int b    = xcd + 8 * (slot >> 5);
    int dt   = slot & 31;
    int tid  = threadIdx.x;

    // ---- stage: agg[b][j][dt*32 .. +31] -> lds[d][j] bf16 (transpose + cast) ----
    const float* src = agg + (size_t)b * N_ * D_ + dt * 32;
    int d4  = tid & 7;               // float4 slot within 32-d row
    int jp0 = tid >> 3;              // 0..23 (j pairs)
#pragma unroll
    for (int p = 0; p < 12; p++) {
        int jp = jp0 + 24 * p;       // 0..287
        int j  = jp * 2;
        float4 v0 = *reinterpret_cast<const float4*>(src + (size_t)j * D_ + d4 * 4);
        float4 v1 = *reinterpret_cast<const float4*>(src + (size_t)(j + 1) * D_ + d4 * 4);
        float a0[4] = { v0.x, v0.y, v0.z, v0.w };
        float a1[4] = { v1.x, v1.y, v1.z, v1.w };
#pragma unroll
        for (int c = 0; c < 4; c++) {
            ushort2 o; o.x = f2bf(a0[c]); o.y = f2bf(a1[c]);
            *reinterpret_cast<ushort2*>(&lds[d4 * 4 + c][j]) = o;
        }
    }
    __syncthreads();

    // ---- GEMM: out[i][n] = sum_j bwn[i][j] * lds[n][j] ----
    int w = tid >> 6;                // wave 0..2, rows w*48..+47
    int lane = tid & 63;
    int g = lane >> 4, r16 = lane & 15;
    const unsigned short* wrow = bwn + (size_t)b * K_ * N_;
    f32x4 acc[3][2] = {};
    for (int kk = 0; kk < N_; kk += 32) {
        bf16x8 afr[3], bfr[2];
#pragma unroll
        for (int mi = 0; mi < 3; mi++)
            afr[mi] = *reinterpret_cast<const bf16x8*>(wrow + (size_t)(w * 48 + mi * 16 + r16) * N_ + kk + g * 8);
#pragma unroll
        for (int s = 0; s < 2; s++)
            bfr[s] = *reinterpret_cast<const bf16x8*>(&lds[s * 16 + r16][kk + g * 8]);
#pragma unroll
        for (int mi = 0; mi < 3; mi++)
#pragma unroll
            for (int s = 0; s < 2; s++)
                acc[mi][s] = __builtin_amdgcn_mfma_f32_16x16x32_bf16(afr[mi], bfr[s], acc[mi][s], 0, 0, 0);
    }
#pragma unroll
    for (int mi = 0; mi < 3; mi++) {
#pragma unroll
        for (int r = 0; r < 4; r++) {
            int i = w * 48 + mi * 16 + g * 4 + r;
            float* orow = out + (size_t)(b * K_ + i) * D_ + dt * 32;
#pragma unroll
            for (int s = 0; s < 2; s++)
                orow[s * 16 + r16] = acc[mi][s][r];
        }
    }
}

extern "C" void kernel_launch(void* const* d_in, const int* in_sizes, int n_in,
                              void* d_out, int out_size, void* d_ws, size_t ws_size,
                              hipStream_t stream) {
    const float* hs_agg = (const float*)d_in[0];
    const float* hs_sim = (const float*)d_in[1];
    const float* metric = (const float*)d_in[2];
    float* out = (float*)d_out;
    char* ws = (char*)d_ws;

    const size_t PN_BYTES  = (size_t)B_ * N_ * D_ * 2;    // 75,497,472
    const size_t BWN_BYTES = (size_t)B_ * K_ * N_ * 2;    // 10,616,832
    unsigned short* pn   = (unsigned short*)ws;
    unsigned short* bwn  = (unsigned short*)(ws + PN_BYTES);
    int* bench_idx = (int*)(ws + PN_BYTES + BWN_BYTES);
    int* high      = (int*)(ws + PN_BYTES + BWN_BYTES + (size_t)B_ * K_ * 4);
    float* out_idx = out + (size_t)B_ * K_ * D_;

    hipLaunchKernelGGL(k_normcast, dim3((B_ * N_) / 4), dim3(256), 0, stream, hs_sim, pn);
    hipLaunchKernelGGL(k_select,   dim3(B_),            dim3(256), 0, stream, metric, bench_idx, high, out_idx);
    hipLaunchKernelGGL(k_sim2,     dim3(B_ * 9),        dim3(256), 0, stream, pn, bench_idx, high, bwn);
    hipLaunchKernelGGL(k_agg2,     dim3(B_ * 32),       dim3(192), 0, stream, bwn, hs_agg, out);
}

// Round 3
// 232.441 us; speedup vs baseline: 1.0476x; 1.0476x over previous
//
#include <hip/hip_runtime.h>
#include <hip/hip_bf16.h>
#include <stdint.h>

#define B_  64
#define N_  576
#define D_  1024
#define K_  144
#define HW_ 24
#define DIST_THR_F 16.733200530681511f

using bf16x8 = __attribute__((ext_vector_type(8))) short;
using f32x4  = __attribute__((ext_vector_type(4))) float;

__device__ __forceinline__ unsigned short f2bf(float f) {
    unsigned u = __float_as_uint(f);
    u += 0x7fffu + ((u >> 16) & 1u);
    return (unsigned short)(u >> 16);
}

__device__ __forceinline__ void pack8(const float4 a, const float4 b, float& ss,
                                      unsigned short* __restrict__ dst) {
    ss += a.x*a.x + a.y*a.y + a.z*a.z + a.w*a.w
        + b.x*b.x + b.y*b.y + b.z*b.z + b.w*b.w;
    union { bf16x8 v; unsigned short u[8]; } pk;
    pk.u[0] = f2bf(a.x); pk.u[1] = f2bf(a.y); pk.u[2] = f2bf(a.z); pk.u[3] = f2bf(a.w);
    pk.u[4] = f2bf(b.x); pk.u[5] = f2bf(b.y); pk.u[6] = f2bf(b.z); pk.u[7] = f2bf(b.w);
    *reinterpret_cast<bf16x8*>(dst) = pk.v;
}

// ---------------- Kernel 1: token selection (one block per batch) ----------------
__global__ __launch_bounds__(256) void k_select(const float* __restrict__ metric,
                                                int* __restrict__ bench_idx,
                                                int* __restrict__ high,
                                                float* __restrict__ out_idx) {
    __shared__ float sm[N_];
    __shared__ float sc[512];
    __shared__ int   si[512];
    __shared__ unsigned smask[18];
    __shared__ int   wpref[18];
    __shared__ float thr_s;
    int b = blockIdx.x, tid = threadIdx.x;
    for (int i = tid; i < N_; i += 256) sm[i] = metric[b * N_ + i];
    if (tid < 18) smask[tid] = 0u;
    __syncthreads();
    if (tid < 144) {
        int ry = tid / 12, rx = tid - ry * 12;
        int base = ry * 48 + rx * 2;
        float vv[4] = { sm[base], sm[base + 1], sm[base + 24], sm[base + 25] };
        int   tk[4] = { base, base + 1, base + 24, base + 25 };
        int a0 = 0;
#pragma unroll
        for (int j = 1; j < 4; j++) if (vv[j] > vv[a0]) a0 = j;
        int a1 = -1;
#pragma unroll
        for (int j = 0; j < 4; j++) {
            if (j == a0) continue;
            if (a1 < 0 || vv[j] > vv[a1]) a1 = j;
        }
        sc[2 * tid]     = vv[a0]; si[2 * tid]     = tk[a0];
        sc[2 * tid + 1] = vv[a1]; si[2 * tid + 1] = tk[a1];
    }
    for (int i = 288 + tid; i < 512; i += 256) { sc[i] = -1e30f; si[i] = 0x7fffffff; }
    __syncthreads();
    for (int k = 2; k <= 512; k <<= 1) {
        for (int j = k >> 1; j > 0; j >>= 1) {
#pragma unroll 2
            for (int t = tid; t < 512; t += 256) {
                int ixj = t ^ j;
                if (ixj > t) {
                    float s1 = sc[t], s2 = sc[ixj];
                    int   i1 = si[t], i2 = si[ixj];
                    bool before = (s1 > s2) || (s1 == s2 && i1 < i2);
                    bool up = ((t & k) == 0);
                    if (up ? !before : before) {
                        sc[t] = s2; sc[ixj] = s1; si[t] = i2; si[ixj] = i1;
                    }
                }
            }
            __syncthreads();
        }
    }
    if (tid == 0) {
        float qpos = 0.55f * 143.0f;
        float g = qpos - 78.0f;
        thr_s = sc[65] * (1.0f - g) + sc[64] * g;
    }
    if (tid < 144) atomicOr(&smask[si[tid] >> 5], 1u << (si[tid] & 31));
    __syncthreads();
    if (tid == 0) {
        int acc = 0;
        for (int w = 0; w < 18; w++) { wpref[w] = acc; acc += __popc(smask[w]); }
    }
    __syncthreads();
    if (tid < 144) {
        int tok = si[tid], w = tok >> 5;
        int rank = wpref[w] + __popc(smask[w] & ((1u << (tok & 31)) - 1u));
        bench_idx[b * K_ + rank] = tok;
        high[b * K_ + rank] = (sc[tid] >= thr_s) ? 1 : 0;
        out_idx[b * K_ + rank] = (float)tok;
    }
}

// ---------------- Kernel 2: LDS-staged sim GEMM from raw f32, norms fused ----------
// block = (b, rt in 3, ct in 3): 48 bench rows x 192 cols. 256 thr / 4 waves.
// Wave w -> cols w*48. BK=64, double-buffered LDS, XOR-swizzled 16B slots.
__global__ __launch_bounds__(256) void k_sim3(const float* __restrict__ hs,
                                              const int* __restrict__ bench_idx,
                                              unsigned short* __restrict__ bwn) {
    __shared__ unsigned short Ab[2][48 * 64];
    __shared__ unsigned short Bb[2][192 * 64];
    __shared__ float ssA[48];
    __shared__ float ssB[192];

    int bid  = blockIdx.x;
    int xcd  = bid & 7;
    int slot = bid >> 3;              // 0..71
    int b    = xcd + 8 * (slot / 9);
    int t9   = slot % 9;
    int rt   = t9 / 3, ct = t9 % 3;
    int tid  = threadIdx.x;
    int w = tid >> 6, lane = tid & 63, g = lane >> 4, r16 = lane & 15;

    if (tid < 48)  ssA[tid] = 0.f;
    if (tid < 192) ssB[tid] = 0.f;

    // staging assignment: chunk = (row, 16B-slot); A: 48*8=384 chunks, B: 192*8=1536
    int rowA0 = tid >> 3;             // 0..31
    int sl    = tid & 7;
    int rowA1 = 32 + rowA0;           // threads < 128 only
    bool hasA1 = (tid < 128);
    const float* base = hs + (size_t)b * N_ * D_;
    int tok0 = bench_idx[b * K_ + rt * 48 + rowA0];
    const float* srcA0 = base + (size_t)tok0 * D_ + sl * 8;
    const float* srcA1 = srcA0;
    if (hasA1) {
        int tok1 = bench_idx[b * K_ + rt * 48 + rowA1];
        srcA1 = base + (size_t)tok1 * D_ + sl * 8;
    }
    const float* srcB[6];
    int rowB[6];
#pragma unroll
    for (int q = 0; q < 6; q++) {
        rowB[q] = (tid >> 3) + 32 * q;
        srcB[q] = base + (size_t)(ct * 192 + rowB[q]) * D_ + sl * 8;
    }
    int aoff0 = rowA0 * 64 + ((sl ^ (rowA0 & 7)) << 3);
    int aoff1 = rowA1 * 64 + ((sl ^ (rowA1 & 7)) << 3);
    int boff[6];
#pragma unroll
    for (int q = 0; q < 6; q++) boff[q] = rowB[q] * 64 + ((sl ^ (rowB[q] & 7)) << 3);

    float4 la0[2], la1[2], lb[6][2];
    float ssa0 = 0.f, ssa1 = 0.f, ssb[6] = {0.f, 0.f, 0.f, 0.f, 0.f, 0.f};

    // prologue: loads for iter 0
    la0[0] = *(const float4*)(srcA0);     la0[1] = *(const float4*)(srcA0 + 4);
    if (hasA1) { la1[0] = *(const float4*)(srcA1); la1[1] = *(const float4*)(srcA1 + 4); }
#pragma unroll
    for (int q = 0; q < 6; q++) {
        lb[q][0] = *(const float4*)(srcB[q]);
        lb[q][1] = *(const float4*)(srcB[q] + 4);
    }

    f32x4 acc[3][3] = {};

#pragma unroll 2
    for (int it = 0; it < 16; ++it) {
        int cur = it & 1;
        // ---- cvt + ss + ds_write phase (consumes loads for iter 'it') ----
        pack8(la0[0], la0[1], ssa0, &Ab[cur][aoff0]);
        if (hasA1) pack8(la1[0], la1[1], ssa1, &Ab[cur][aoff1]);
#pragma unroll
        for (int q = 0; q < 6; q++) pack8(lb[q][0], lb[q][1], ssb[q], &Bb[cur][boff[q]]);
        __syncthreads();
        // ---- issue next-tile loads (fly under the MFMA phase) ----
        if (it < 15) {
            int kb = (it + 1) * 64;
            la0[0] = *(const float4*)(srcA0 + kb); la0[1] = *(const float4*)(srcA0 + kb + 4);
            if (hasA1) { la1[0] = *(const float4*)(srcA1 + kb); la1[1] = *(const float4*)(srcA1 + kb + 4); }
#pragma unroll
            for (int q = 0; q < 6; q++) {
                lb[q][0] = *(const float4*)(srcB[q] + kb);
                lb[q][1] = *(const float4*)(srcB[q] + kb + 4);
            }
        }
        // ---- MFMA phase: read swizzled fragments from buf[cur] ----
#pragma unroll
        for (int h = 0; h < 2; h++) {
            bf16x8 af[3], bfv[3];
#pragma unroll
            for (int mi = 0; mi < 3; mi++) {
                int row = mi * 16 + r16;
                af[mi] = *(const bf16x8*)&Ab[cur][row * 64 + (((h * 4 + g) ^ (row & 7)) << 3)];
            }
#pragma unroll
            for (int nj = 0; nj < 3; nj++) {
                int row = w * 48 + nj * 16 + r16;
                bfv[nj] = *(const bf16x8*)&Bb[cur][row * 64 + (((h * 4 + g) ^ (row & 7)) << 3)];
            }
#pragma unroll
            for (int mi = 0; mi < 3; mi++)
#pragma unroll
                for (int nj = 0; nj < 3; nj++)
                    acc[mi][nj] = __builtin_amdgcn_mfma_f32_16x16x32_bf16(af[mi], bfv[nj], acc[mi][nj], 0, 0, 0);
        }
    }

    // ---- norm reduction ----
    atomicAdd(&ssA[rowA0], ssa0);
    if (hasA1) atomicAdd(&ssA[rowA1], ssa1);
#pragma unroll
    for (int q = 0; q < 6; q++) atomicAdd(&ssB[rowB[q]], ssb[q]);
    __syncthreads();

    // ---- epilogue: scale by 1/(|xi||xj|), relu, penalty, write bf16 ----
    float invB3[3];
#pragma unroll
    for (int nj = 0; nj < 3; nj++)
        invB3[nj] = 1.0f / fmaxf(sqrtf(ssB[w * 48 + nj * 16 + r16]), 1e-12f);
    int col0 = ct * 192 + w * 48;
#pragma unroll
    for (int mi = 0; mi < 3; mi++) {
#pragma unroll
        for (int r = 0; r < 4; r++) {
            int lrow = mi * 16 + g * 4 + r;
            int i = rt * 48 + lrow;
            int ti = bench_idx[b * K_ + i];
            float invA = 1.0f / fmaxf(sqrtf(ssA[lrow]), 1e-12f);
            int y1 = ti / HW_, x1 = ti % HW_;
            unsigned short* prow = bwn + (size_t)(b * K_ + i) * N_;
#pragma unroll
            for (int nj = 0; nj < 3; nj++) {
                int col = col0 + nj * 16 + r16;
                int y2 = col / HW_, x2 = col % HW_;
                float dy = (float)(y1 - y2), dx = (float)(x1 - x2);
                float dist = sqrtf(dy * dy + dx * dx);
                float pen = 1.0f - fminf(dist / DIST_THR_F, 1.0f);
                float val = fmaxf(acc[mi][nj][r], 0.0f) * invA * invB3[nj] * pen;
                prow[col] = f2bf(val);
            }
        }
    }
}

// ---------------- Kernel 3: per-row normalize (in place, bf16); high rows -> one-hot ----
__global__ __launch_bounds__(256) void k_norm(unsigned short* __restrict__ bwn,
                                              const int* __restrict__ bench_idx,
                                              const int* __restrict__ high) {
    int row  = blockIdx.x * 4 + (threadIdx.x >> 6);
    int lane = threadIdx.x & 63;
    int tok = bench_idx[row];
    int hi  = high[row];
    unsigned short* pr = bwn + (size_t)row * N_;
    if (hi) {
#pragma unroll
        for (int q = 0; q < 9; q++) {
            int j = lane + 64 * q;
            pr[j] = (j == tok) ? (unsigned short)0x3F80 : (unsigned short)0;
        }
    } else {
        float v[9];
        float s = 0.f;
#pragma unroll
        for (int q = 0; q < 9; q++) {
            v[q] = __uint_as_float((unsigned)pr[lane + 64 * q] << 16);
            s += v[q];
        }
#pragma unroll
        for (int m = 32; m >= 1; m >>= 1) s += __shfl_xor(s, m, 64);
        float scale = 1.0f / (s + 1e-8f);
#pragma unroll
        for (int q = 0; q < 9; q++) {
            int j = lane + 64 * q;
            pr[j] = (j == tok) ? (unsigned short)0x3F80 : f2bf(v[q] * scale);
        }
    }
}

// ---------------- Kernel 4: aggregation GEMM, fused transpose+cast, 16-d panels -------
// block = (b, dt in 64): out rows 0..143, d cols dt*16..+15. 192 thr / 3 waves.
__global__ __launch_bounds__(192) void k_agg3(const unsigned short* __restrict__ bwn,
                                              const float* __restrict__ agg,
                                              float* __restrict__ out) {
    __shared__ unsigned short lds[16][584];   // dword stride 292 == 4 mod 32
    int bid  = blockIdx.x;
    int xcd  = bid & 7;
    int slot = bid >> 3;              // 0..511
    int b    = xcd + 8 * (slot >> 6);
    int dt   = slot & 63;
    int tid  = threadIdx.x;

    // ---- stage: agg[b][j][dt*16 .. +15] -> lds[d][j] bf16 (transpose + cast) ----
    const float* src = agg + (size_t)b * N_ * D_ + dt * 16;
    int d4  = tid & 3;                // float4 slot within 16-d row
    int jp0 = tid >> 2;               // 0..47
#pragma unroll
    for (int p = 0; p < 6; p++) {
        int jp = jp0 + 48 * p;        // 0..287
        int j  = jp * 2;
        float4 v0 = *reinterpret_cast<const float4*>(src + (size_t)j * D_ + d4 * 4);
        float4 v1 = *reinterpret_cast<const float4*>(src + (size_t)(j + 1) * D_ + d4 * 4);
        float a0[4] = { v0.x, v0.y, v0.z, v0.w };
        float a1[4] = { v1.x, v1.y, v1.z, v1.w };
#pragma unroll
        for (int c = 0; c < 4; c++) {
            ushort2 o; o.x = f2bf(a0[c]); o.y = f2bf(a1[c]);
            *reinterpret_cast<ushort2*>(&lds[d4 * 4 + c][j]) = o;
        }
    }
    __syncthreads();

    // ---- GEMM: out[i][dt*16+n] = sum_j bwn[i][j] * lds[n][j] ----
    int w = tid >> 6;                 // wave 0..2 -> rows w*48..+47
    int lane = tid & 63;
    int g = lane >> 4, r16 = lane & 15;
    const unsigned short* wrow = bwn + (size_t)b * K_ * N_;
    f32x4 acc[3] = {};
    for (int kk = 0; kk < N_; kk += 32) {
        bf16x8 afr[3];
#pragma unroll
        for (int mi = 0; mi < 3; mi++)
            afr[mi] = *reinterpret_cast<const bf16x8*>(wrow + (size_t)(w * 48 + mi * 16 + r16) * N_ + kk + g * 8);
        bf16x8 bfr = *reinterpret_cast<const bf16x8*>(&lds[r16][kk + g * 8]);
#pragma unroll
        for (int mi = 0; mi < 3; mi++)
            acc[mi] = __builtin_amdgcn_mfma_f32_16x16x32_bf16(afr[mi], bfr, acc[mi], 0, 0, 0);
    }
#pragma unroll
    for (int mi = 0; mi < 3; mi++) {
#pragma unroll
        for (int r = 0; r < 4; r++) {
            int i = w * 48 + mi * 16 + g * 4 + r;
            out[(size_t)(b * K_ + i) * D_ + dt * 16 + r16] = acc[mi][r];
        }
    }
}

extern "C" void kernel_launch(void* const* d_in, const int* in_sizes, int n_in,
                              void* d_out, int out_size, void* d_ws, size_t ws_size,
                              hipStream_t stream) {
    const float* hs_agg = (const float*)d_in[0];
    const float* hs_sim = (const float*)d_in[1];
    const float* metric = (const float*)d_in[2];
    float* out = (float*)d_out;
    char* ws = (char*)d_ws;

    const size_t BWN_BYTES = (size_t)B_ * K_ * N_ * 2;    // 10,616,832
    unsigned short* bwn = (unsigned short*)ws;
    int* bench_idx = (int*)(ws + BWN_BYTES);
    int* high      = (int*)(ws + BWN_BYTES + (size_t)B_ * K_ * 4);
    float* out_idx = out + (size_t)B_ * K_ * D_;

    hipLaunchKernelGGL(k_select, dim3(B_),            dim3(256), 0, stream, metric, bench_idx, high, out_idx);
    hipLaunchKernelGGL(k_sim3,   dim3(B_ * 9),        dim3(256), 0, stream, hs_sim, bench_idx, bwn);
    hipLaunchKernelGGL(k_norm,   dim3((B_ * K_) / 4), dim3(256), 0, stream, bwn, bench_idx, high);
    hipLaunchKernelGGL(k_agg3,   dim3(B_ * 64),       dim3(192), 0, stream, bwn, hs_agg, out);
}

// Round 4
// 137.180 us; speedup vs baseline: 1.7751x; 1.6944x over previous
//
#include <hip/hip_runtime.h>
#include <hip/hip_bf16.h>
#include <stdint.h>

#define B_  64
#define N_  576
#define D_  1024
#define K_  144
#define HW_ 24
#define DIST_THR_F 16.733200530681511f

using bf16x8 = __attribute__((ext_vector_type(8))) short;
using f32x4  = __attribute__((ext_vector_type(4))) float;

__device__ __forceinline__ unsigned short f2bf(float f) {
    unsigned u = __float_as_uint(f);
    u += 0x7fffu + ((u >> 16) & 1u);
    return (unsigned short)(u >> 16);
}

// ---------------- Kernel 1: row L2-normalize hs_sim and cast to bf16 ----------------
__global__ __launch_bounds__(256) void k_normcast(const float* __restrict__ x,
                                                  unsigned short* __restrict__ pn) {
    int row  = blockIdx.x * 4 + (threadIdx.x >> 6);
    int lane = threadIdx.x & 63;
    const float4* src = reinterpret_cast<const float4*>(x + (size_t)row * D_);
    float4 v[4];
    float ss = 0.f;
#pragma unroll
    for (int q = 0; q < 4; q++) {
        v[q] = src[lane + 64 * q];
        ss += v[q].x * v[q].x + v[q].y * v[q].y + v[q].z * v[q].z + v[q].w * v[q].w;
    }
#pragma unroll
    for (int m = 32; m >= 1; m >>= 1) ss += __shfl_xor(ss, m, 64);
    float inv = 1.0f / fmaxf(sqrtf(ss), 1e-12f);
    ushort4* dst = reinterpret_cast<ushort4*>(pn + (size_t)row * D_);
#pragma unroll
    for (int q = 0; q < 4; q++) {
        ushort4 o;
        o.x = f2bf(v[q].x * inv); o.y = f2bf(v[q].y * inv);
        o.z = f2bf(v[q].z * inv); o.w = f2bf(v[q].w * inv);
        dst[lane + 64 * q] = o;
    }
}

// ---------------- Kernel 2: token selection (one block per batch) ----------------
__global__ __launch_bounds__(256) void k_select(const float* __restrict__ metric,
                                                int* __restrict__ bench_idx,
                                                int* __restrict__ high,
                                                float* __restrict__ out_idx) {
    __shared__ float sm[N_];
    __shared__ float sc[512];
    __shared__ int   si[512];
    __shared__ unsigned smask[18];
    __shared__ int   wpref[18];
    __shared__ float thr_s;
    int b = blockIdx.x, tid = threadIdx.x;
    for (int i = tid; i < N_; i += 256) sm[i] = metric[b * N_ + i];
    if (tid < 18) smask[tid] = 0u;
    __syncthreads();
    if (tid < 144) {
        int ry = tid / 12, rx = tid - ry * 12;
        int base = ry * 48 + rx * 2;
        float vv[4] = { sm[base], sm[base + 1], sm[base + 24], sm[base + 25] };
        int   tk[4] = { base, base + 1, base + 24, base + 25 };
        int a0 = 0;
#pragma unroll
        for (int j = 1; j < 4; j++) if (vv[j] > vv[a0]) a0 = j;
        int a1 = -1;
#pragma unroll
        for (int j = 0; j < 4; j++) {
            if (j == a0) continue;
            if (a1 < 0 || vv[j] > vv[a1]) a1 = j;
        }
        sc[2 * tid]     = vv[a0]; si[2 * tid]     = tk[a0];
        sc[2 * tid + 1] = vv[a1]; si[2 * tid + 1] = tk[a1];
    }
    for (int i = 288 + tid; i < 512; i += 256) { sc[i] = -1e30f; si[i] = 0x7fffffff; }
    __syncthreads();
    for (int k = 2; k <= 512; k <<= 1) {
        for (int j = k >> 1; j > 0; j >>= 1) {
#pragma unroll 2
            for (int t = tid; t < 512; t += 256) {
                int ixj = t ^ j;
                if (ixj > t) {
                    float s1 = sc[t], s2 = sc[ixj];
                    int   i1 = si[t], i2 = si[ixj];
                    bool before = (s1 > s2) || (s1 == s2 && i1 < i2);
                    bool up = ((t & k) == 0);
                    if (up ? !before : before) {
                        sc[t] = s2; sc[ixj] = s1; si[t] = i2; si[ixj] = i1;
                    }
                }
            }
            __syncthreads();
        }
    }
    if (tid == 0) {
        float qpos = 0.55f * 143.0f;
        float g = qpos - 78.0f;
        thr_s = sc[65] * (1.0f - g) + sc[64] * g;
    }
    if (tid < 144) atomicOr(&smask[si[tid] >> 5], 1u << (si[tid] & 31));
    __syncthreads();
    if (tid == 0) {
        int acc = 0;
        for (int w = 0; w < 18; w++) { wpref[w] = acc; acc += __popc(smask[w]); }
    }
    __syncthreads();
    if (tid < 144) {
        int tok = si[tid], w = tok >> 5;
        int rank = wpref[w] + __popc(smask[w] & ((1u << (tok & 31)) - 1u));
        bench_idx[b * K_ + rank] = tok;
        high[b * K_ + rank] = (sc[tid] >= thr_s) ? 1 : 0;
        out_idx[b * K_ + rank] = (float)tok;
    }
}

// ---------------- Kernel 3: sim GEMM (bf16 pn) + relu*penalty -> bwn ----------------
// block = (b, ct in 0..2): 144 bench rows x 192 cols. 384 thr / 6 waves (3x2 wave grid).
// Single LDS tile [336 rows][64 bf16] (A rows 0..143 gathered, B rows 144..335),
// register-double-buffered, 2 syncs/iter; next-tile loads fly under MFMA phase.
// XOR slot swizzle: physical slot p holds logical slot p^(row&7).
__global__ __launch_bounds__(384) void k_sim4(const unsigned short* __restrict__ pn,
                                              const int* __restrict__ bench_idx,
                                              unsigned short* __restrict__ bwn) {
    __shared__ unsigned short SM[336 * 64];
    int bid  = blockIdx.x;
    int xcd  = bid & 7;
    int s    = bid >> 3;               // 0..23
    int ct   = s % 3;
    int b    = (s / 3) * 8 + xcd;
    int tid  = threadIdx.x;
    int w = tid >> 6, lane = tid & 63, g = lane >> 4, r16 = lane & 15;
    int wr = w >> 1, wc = w & 1;       // 3x2 wave grid: rows wr*48, cols wc*96

    const unsigned short* pnb = pn + (size_t)b * N_ * D_;

    // stage setup: 2688 16B-chunks = 384 thr x 7
    const unsigned short* gsrc[7];
    int dsoff[7];
#pragma unroll
    for (int q = 0; q < 7; q++) {
        int cid = tid + 384 * q;
        int row = cid >> 3;            // 0..335
        int p   = cid & 7;             // physical slot
        int l   = p ^ (row & 7);       // logical slot in global row
        int tok = (row < 144) ? bench_idx[b * K_ + row] : (ct * 192 + (row - 144));
        gsrc[q]  = pnb + (size_t)tok * D_ + l * 8;
        dsoff[q] = row * 64 + p * 8;
    }

    bf16x8 sreg[7];
#pragma unroll
    for (int q = 0; q < 7; q++) sreg[q] = *(const bf16x8*)(gsrc[q]);

    f32x4 acc[3][6] = {};

    for (int t = 0; t < 16; ++t) {
        // write tile t
#pragma unroll
        for (int q = 0; q < 7; q++) *(bf16x8*)&SM[dsoff[q]] = sreg[q];
        __syncthreads();
        // issue next-tile loads (fly under MFMA)
        if (t < 15) {
            int kb = (t + 1) * 64;
#pragma unroll
            for (int q = 0; q < 7; q++) sreg[q] = *(const bf16x8*)(gsrc[q] + kb);
        }
        // MFMA phase
#pragma unroll
        for (int h = 0; h < 2; h++) {
            int ks = h * 4 + g;
            bf16x8 af[3], bf[6];
#pragma unroll
            for (int mi = 0; mi < 3; mi++) {
                int row = wr * 48 + mi * 16 + r16;
                af[mi] = *(const bf16x8*)&SM[row * 64 + (ks ^ (row & 7)) * 8];
            }
#pragma unroll
            for (int nj = 0; nj < 6; nj++) {
                int row = 144 + wc * 96 + nj * 16 + r16;
                bf[nj] = *(const bf16x8*)&SM[row * 64 + (ks ^ (row & 7)) * 8];
            }
#pragma unroll
            for (int mi = 0; mi < 3; mi++)
#pragma unroll
                for (int nj = 0; nj < 6; nj++)
                    acc[mi][nj] = __builtin_amdgcn_mfma_f32_16x16x32_bf16(af[mi], bf[nj], acc[mi][nj], 0, 0, 0);
        }
        __syncthreads();
    }

    // epilogue: relu * distance penalty, write bf16
#pragma unroll
    for (int mi = 0; mi < 3; mi++) {
#pragma unroll
        for (int r = 0; r < 4; r++) {
            int i = wr * 48 + mi * 16 + g * 4 + r;
            int ti = bench_idx[b * K_ + i];
            int y1 = ti / HW_, x1 = ti % HW_;
            unsigned short* prow = bwn + (size_t)(b * K_ + i) * N_;
#pragma unroll
            for (int nj = 0; nj < 6; nj++) {
                int col = ct * 192 + wc * 96 + nj * 16 + r16;
                int y2 = col / HW_, x2 = col % HW_;
                float dy = (float)(y1 - y2), dx = (float)(x1 - x2);
                float dist = sqrtf(dy * dy + dx * dx);
                float pen = 1.0f - fminf(dist / DIST_THR_F, 1.0f);
                float val = fmaxf(acc[mi][nj][r], 0.0f) * pen;
                prow[col] = f2bf(val);
            }
        }
    }
}

// ---------------- Kernel 4: per-row normalize (in place); high rows -> one-hot ----
__global__ __launch_bounds__(256) void k_norm(unsigned short* __restrict__ bwn,
                                              const int* __restrict__ bench_idx,
                                              const int* __restrict__ high) {
    int row  = blockIdx.x * 4 + (threadIdx.x >> 6);
    int lane = threadIdx.x & 63;
    int tok = bench_idx[row];
    int hi  = high[row];
    unsigned short* pr = bwn + (size_t)row * N_;
    if (hi) {
#pragma unroll
        for (int q = 0; q < 9; q++) {
            int j = lane + 64 * q;
            pr[j] = (j == tok) ? (unsigned short)0x3F80 : (unsigned short)0;
        }
    } else {
        float v[9];
        float s = 0.f;
#pragma unroll
        for (int q = 0; q < 9; q++) {
            v[q] = __uint_as_float((unsigned)pr[lane + 64 * q] << 16);
            s += v[q];
        }
#pragma unroll
        for (int m = 32; m >= 1; m >>= 1) s += __shfl_xor(s, m, 64);
        float scale = 1.0f / (s + 1e-8f);
#pragma unroll
        for (int q = 0; q < 9; q++) {
            int j = lane + 64 * q;
            pr[j] = (j == tok) ? (unsigned short)0x3F80 : f2bf(v[q] * scale);
        }
    }
}

// ---------------- Kernel 5: aggregation GEMM with fused f32->bf16 transpose ---------
// block = (b, dt in 0..3): 144 rows x 256 d-cols. 384 thr / 6 waves (3x2).
// A = bwn [144][BK=64 j] reg-staged to LDS (slot swizzle p^(row&7));
// B = agg^T [256 d][64 j] built in LDS from pair-of-rows f32 loads, swizzle
// s = (j>>3)^(d&7)^((d>>3)&7). Single buffers, 2 syncs/iter, loads fly under MFMA.
__global__ __launch_bounds__(384) void k_agg4(const unsigned short* __restrict__ bwn,
                                              const float* __restrict__ agg,
                                              float* __restrict__ out) {
    __shared__ unsigned short LA[144 * 64];
    __shared__ unsigned int   LB[256 * 32];     // [d][32 u32 of j-pairs]
    int bid  = blockIdx.x;
    int xcd  = bid & 7;
    int s    = bid >> 3;               // 0..31
    int dt   = s & 3;
    int b    = (s >> 2) * 8 + xcd;
    int tid  = threadIdx.x;
    int w = tid >> 6, lane = tid & 63, g = lane >> 4, r16 = lane & 15;
    int wr = w >> 1, wc = w & 1;       // rows wr*48, d-cols wc*128

    // A-stage setup: 1152 chunks = 384 x 3
    const unsigned short* asrc[3];
    int adso[3];
#pragma unroll
    for (int q = 0; q < 3; q++) {
        int cid = tid + 384 * q;
        int row = cid >> 3, p = cid & 7, l = p ^ (row & 7);
        asrc[q] = bwn + (size_t)(b * K_ + row) * N_ + l * 8;
        adso[q] = row * 64 + p * 8;
    }
    // B-stage: pair pp = w + 6u (u=0..5), lane covers d-cols 4*lane..+3
    const float* bbase = agg + (size_t)b * N_ * D_ + dt * 256 + lane * 4;

    bf16x8 areg[3];
    float4 breg[6][2];
#pragma unroll
    for (int q = 0; q < 3; q++) areg[q] = *(const bf16x8*)(asrc[q]);
#pragma unroll
    for (int u = 0; u < 6; u++) {
        int pp = w + 6 * u;
        if (pp < 32) {
            breg[u][0] = *(const float4*)(bbase + (size_t)(2 * pp) * D_);
            breg[u][1] = *(const float4*)(bbase + (size_t)(2 * pp + 1) * D_);
        }
    }

    f32x4 acc[3][8] = {};

    for (int t = 0; t < 9; ++t) {
        // ---- write tile t to LDS ----
#pragma unroll
        for (int q = 0; q < 3; q++) *(bf16x8*)&LA[adso[q]] = areg[q];
#pragma unroll
        for (int u = 0; u < 6; u++) {
            int pp = w + 6 * u;
            if (pp < 32) {
                float a0[4] = { breg[u][0].x, breg[u][0].y, breg[u][0].z, breg[u][0].w };
                float a1[4] = { breg[u][1].x, breg[u][1].y, breg[u][1].z, breg[u][1].w };
                int js = pp >> 2;                  // (2pp)>>3
#pragma unroll
                for (int c = 0; c < 4; c++) {
                    int d = lane * 4 + c;
                    int sw = (js ^ (d & 7) ^ ((d >> 3) & 7)) & 7;
                    unsigned pk = (unsigned)f2bf(a0[c]) | ((unsigned)f2bf(a1[c]) << 16);
                    LB[d * 32 + sw * 4 + (pp & 3)] = pk;
                }
            }
        }
        __syncthreads();
        // ---- issue next-tile loads ----
        if (t < 8) {
            int kb = (t + 1) * 64;
#pragma unroll
            for (int q = 0; q < 3; q++) areg[q] = *(const bf16x8*)(asrc[q] + kb);
#pragma unroll
            for (int u = 0; u < 6; u++) {
                int pp = w + 6 * u;
                if (pp < 32) {
                    breg[u][0] = *(const float4*)(bbase + (size_t)(kb + 2 * pp) * D_);
                    breg[u][1] = *(const float4*)(bbase + (size_t)(kb + 2 * pp + 1) * D_);
                }
            }
        }
        // ---- MFMA phase ----
#pragma unroll
        for (int h = 0; h < 2; h++) {
            int ks = h * 4 + g;
            bf16x8 af[3], bf[8];
#pragma unroll
            for (int mi = 0; mi < 3; mi++) {
                int row = wr * 48 + mi * 16 + r16;
                af[mi] = *(const bf16x8*)&LA[row * 64 + (ks ^ (row & 7)) * 8];
            }
#pragma unroll
            for (int nj = 0; nj < 8; nj++) {
                int d = wc * 128 + nj * 16 + r16;
                int sw = (ks ^ (d & 7) ^ ((d >> 3) & 7)) & 7;
                bf[nj] = *(const bf16x8*)&LB[d * 32 + sw * 4];
            }
#pragma unroll
            for (int mi = 0; mi < 3; mi++)
#pragma unroll
                for (int nj = 0; nj < 8; nj++)
                    acc[mi][nj] = __builtin_amdgcn_mfma_f32_16x16x32_bf16(af[mi], bf[nj], acc[mi][nj], 0, 0, 0);
        }
        __syncthreads();
    }

    // epilogue
#pragma unroll
    for (int mi = 0; mi < 3; mi++) {
#pragma unroll
        for (int r = 0; r < 4; r++) {
            int i = wr * 48 + mi * 16 + g * 4 + r;
            float* orow = out + (size_t)(b * K_ + i) * D_ + dt * 256 + wc * 128;
#pragma unroll
            for (int nj = 0; nj < 8; nj++)
                orow[nj * 16 + r16] = acc[mi][nj][r];
        }
    }
}

extern "C" void kernel_launch(void* const* d_in, const int* in_sizes, int n_in,
                              void* d_out, int out_size, void* d_ws, size_t ws_size,
                              hipStream_t stream) {
    const float* hs_agg = (const float*)d_in[0];
    const float* hs_sim = (const float*)d_in[1];
    const float* metric = (const float*)d_in[2];
    float* out = (float*)d_out;
    char* ws = (char*)d_ws;

    const size_t PN_BYTES  = (size_t)B_ * N_ * D_ * 2;    // 75,497,472
    const size_t BWN_BYTES = (size_t)B_ * K_ * N_ * 2;    // 10,616,832
    unsigned short* pn  = (unsigned short*)ws;
    unsigned short* bwn = (unsigned short*)(ws + PN_BYTES);
    int* bench_idx = (int*)(ws + PN_BYTES + BWN_BYTES);
    int* high      = (int*)(ws + PN_BYTES + BWN_BYTES + (size_t)B_ * K_ * 4);
    float* out_idx = out + (size_t)B_ * K_ * D_;

    hipLaunchKernelGGL(k_normcast, dim3((B_ * N_) / 4), dim3(256), 0, stream, hs_sim, pn);
    hipLaunchKernelGGL(k_select,   dim3(B_),            dim3(256), 0, stream, metric, bench_idx, high, out_idx);
    hipLaunchKernelGGL(k_sim4,     dim3(B_ * 3),        dim3(384), 0, stream, pn, bench_idx, bwn);
    hipLaunchKernelGGL(k_norm,     dim3((B_ * K_) / 4), dim3(256), 0, stream, bwn, bench_idx, high);
    hipLaunchKernelGGL(k_agg4,     dim3(B_ * 4),        dim3(384), 0, stream, bwn, hs_agg, out);
}

// Round 5
// 129.632 us; speedup vs baseline: 1.8784x; 1.0582x over previous
//
#include <hip/hip_runtime.h>
#include <hip/hip_bf16.h>
#include <stdint.h>

#define B_  64
#define N_  576
#define D_  1024
#define K_  144
#define HW_ 24
#define DIST_THR_F 16.733200530681511f

using bf16x8 = __attribute__((ext_vector_type(8))) short;
using f32x4  = __attribute__((ext_vector_type(4))) float;

__device__ __forceinline__ unsigned short f2bf(float f) {
    unsigned u = __float_as_uint(f);
    u += 0x7fffu + ((u >> 16) & 1u);
    return (unsigned short)(u >> 16);
}

__device__ __forceinline__ void pack8(const float4 a, const float4 b, float& ss,
                                      unsigned short* __restrict__ dst) {
    ss += a.x*a.x + a.y*a.y + a.z*a.z + a.w*a.w
        + b.x*b.x + b.y*b.y + b.z*b.z + b.w*b.w;
    union { bf16x8 v; unsigned short u[8]; } pk;
    pk.u[0] = f2bf(a.x); pk.u[1] = f2bf(a.y); pk.u[2] = f2bf(a.z); pk.u[3] = f2bf(a.w);
    pk.u[4] = f2bf(b.x); pk.u[5] = f2bf(b.y); pk.u[6] = f2bf(b.z); pk.u[7] = f2bf(b.w);
    *reinterpret_cast<bf16x8*>(dst) = pk.v;
}

// ---------------- Kernel 1: token selection (one block per batch) ----------------
// Also zeroes the per-row weight-sum accumulator for this batch (graph-replay safe).
__global__ __launch_bounds__(256) void k_select(const float* __restrict__ metric,
                                                int* __restrict__ bench_idx,
                                                int* __restrict__ high,
                                                float* __restrict__ out_idx,
                                                float* __restrict__ rowsum) {
    __shared__ float sm[N_];
    __shared__ float sc[512];
    __shared__ int   si[512];
    __shared__ unsigned smask[18];
    __shared__ int   wpref[18];
    __shared__ float thr_s;
    int b = blockIdx.x, tid = threadIdx.x;
    for (int i = tid; i < N_; i += 256) sm[i] = metric[b * N_ + i];
    if (tid < 18) smask[tid] = 0u;
    if (tid < 144) rowsum[b * K_ + tid] = 0.f;
    __syncthreads();
    if (tid < 144) {
        int ry = tid / 12, rx = tid - ry * 12;
        int base = ry * 48 + rx * 2;
        float vv[4] = { sm[base], sm[base + 1], sm[base + 24], sm[base + 25] };
        int   tk[4] = { base, base + 1, base + 24, base + 25 };
        int a0 = 0;
#pragma unroll
        for (int j = 1; j < 4; j++) if (vv[j] > vv[a0]) a0 = j;
        int a1 = -1;
#pragma unroll
        for (int j = 0; j < 4; j++) {
            if (j == a0) continue;
            if (a1 < 0 || vv[j] > vv[a1]) a1 = j;
        }
        sc[2 * tid]     = vv[a0]; si[2 * tid]     = tk[a0];
        sc[2 * tid + 1] = vv[a1]; si[2 * tid + 1] = tk[a1];
    }
    for (int i = 288 + tid; i < 512; i += 256) { sc[i] = -1e30f; si[i] = 0x7fffffff; }
    __syncthreads();
    for (int k = 2; k <= 512; k <<= 1) {
        for (int j = k >> 1; j > 0; j >>= 1) {
#pragma unroll 2
            for (int t = tid; t < 512; t += 256) {
                int ixj = t ^ j;
                if (ixj > t) {
                    float s1 = sc[t], s2 = sc[ixj];
                    int   i1 = si[t], i2 = si[ixj];
                    bool before = (s1 > s2) || (s1 == s2 && i1 < i2);
                    bool up = ((t & k) == 0);
                    if (up ? !before : before) {
                        sc[t] = s2; sc[ixj] = s1; si[t] = i2; si[ixj] = i1;
                    }
                }
            }
            __syncthreads();
        }
    }
    if (tid == 0) {
        float qpos = 0.55f * 143.0f;
        float g = qpos - 78.0f;
        thr_s = sc[65] * (1.0f - g) + sc[64] * g;
    }
    if (tid < 144) atomicOr(&smask[si[tid] >> 5], 1u << (si[tid] & 31));
    __syncthreads();
    if (tid == 0) {
        int acc = 0;
        for (int w = 0; w < 18; w++) { wpref[w] = acc; acc += __popc(smask[w]); }
    }
    __syncthreads();
    if (tid < 144) {
        int tok = si[tid], w = tok >> 5;
        int rank = wpref[w] + __popc(smask[w] & ((1u << (tok & 31)) - 1u));
        bench_idx[b * K_ + rank] = tok;
        high[b * K_ + rank] = (sc[tid] >= thr_s) ? 1 : 0;
        out_idx[b * K_ + rank] = (float)tok;
    }
}

// ---------------- Kernel 2: fused normalize + sim GEMM + penalty -> bwn -------------
// block = (b, ct in 0..2): 144 bench rows x 192 cols. 384 thr / 6 waves (3x2).
// Stages raw f32 -> bf16 into LDS with in-flight sum(x^2) per row; norms applied in
// epilogue. Writes UNNORMALIZED weights (self col = 0, high rows = 0) and atomically
// accumulates f32 row sums into rowsum[b][i]. Skeleton identical to round-4's k_sim4.
__global__ __launch_bounds__(384) void k_sim5(const float* __restrict__ hs,
                                              const int* __restrict__ bench_idx,
                                              const int* __restrict__ high,
                                              unsigned short* __restrict__ bwn,
                                              float* __restrict__ rowsum) {
    __shared__ unsigned short SM[336 * 64];
    __shared__ float ssL[336];
    __shared__ float rsum[144];
    int bid  = blockIdx.x;
    int xcd  = bid & 7;
    int s    = bid >> 3;               // 0..23
    int ct   = s % 3;
    int b    = (s / 3) * 8 + xcd;
    int tid  = threadIdx.x;
    int w = tid >> 6, lane = tid & 63, g = lane >> 4, r16 = lane & 15;
    int wr = w >> 1, wc = w & 1;       // 3x2 wave grid: rows wr*48, cols wc*96

    if (tid < 336) ssL[tid] = 0.f;
    if (tid < 144) rsum[tid] = 0.f;

    const float* base = hs + (size_t)b * N_ * D_;

    // stage setup: 2688 16B-bf16-chunks = 384 thr x 7; chunk q <- 32B of f32
    const float* gsrc[7];
    int dsoff[7];
#pragma unroll
    for (int q = 0; q < 7; q++) {
        int cid = tid + 384 * q;
        int row = cid >> 3;            // 0..335
        int p   = cid & 7;             // physical slot
        int l   = p ^ (row & 7);       // logical slot
        int tok = (row < 144) ? bench_idx[b * K_ + row] : (ct * 192 + (row - 144));
        gsrc[q]  = base + (size_t)tok * D_ + l * 8;
        dsoff[q] = row * 64 + p * 8;
    }

    float4 fa[7][2];
    float ssp[7] = {0.f, 0.f, 0.f, 0.f, 0.f, 0.f, 0.f};
#pragma unroll
    for (int q = 0; q < 7; q++) {
        fa[q][0] = *(const float4*)(gsrc[q]);
        fa[q][1] = *(const float4*)(gsrc[q] + 4);
    }

    f32x4 acc[3][6] = {};

    for (int t = 0; t < 16; ++t) {
        // pack + write tile t
#pragma unroll
        for (int q = 0; q < 7; q++) pack8(fa[q][0], fa[q][1], ssp[q], &SM[dsoff[q]]);
        __syncthreads();
        // issue next-tile loads (fly under MFMA)
        if (t < 15) {
            int kb = (t + 1) * 64;
#pragma unroll
            for (int q = 0; q < 7; q++) {
                fa[q][0] = *(const float4*)(gsrc[q] + kb);
                fa[q][1] = *(const float4*)(gsrc[q] + kb + 4);
            }
        }
        // MFMA phase
#pragma unroll
        for (int h = 0; h < 2; h++) {
            int ks = h * 4 + g;
            bf16x8 af[3], bf[6];
#pragma unroll
            for (int mi = 0; mi < 3; mi++) {
                int row = wr * 48 + mi * 16 + r16;
                af[mi] = *(const bf16x8*)&SM[row * 64 + (ks ^ (row & 7)) * 8];
            }
#pragma unroll
            for (int nj = 0; nj < 6; nj++) {
                int row = 144 + wc * 96 + nj * 16 + r16;
                bf[nj] = *(const bf16x8*)&SM[row * 64 + (ks ^ (row & 7)) * 8];
            }
#pragma unroll
            for (int mi = 0; mi < 3; mi++)
#pragma unroll
                for (int nj = 0; nj < 6; nj++)
                    acc[mi][nj] = __builtin_amdgcn_mfma_f32_16x16x32_bf16(af[mi], bf[nj], acc[mi][nj], 0, 0, 0);
        }
        __syncthreads();
    }

    // accumulate per-row sum(x^2) into LDS
#pragma unroll
    for (int q = 0; q < 7; q++) {
        int row = (tid + 384 * q) >> 3;
        atomicAdd(&ssL[row], ssp[q]);
    }
    __syncthreads();

    // epilogue: val = relu(acc)*invA*invB*pen; row-sum; write (self=0, high rows=0)
    float invB6[6];
#pragma unroll
    for (int nj = 0; nj < 6; nj++)
        invB6[nj] = 1.0f / fmaxf(sqrtf(ssL[144 + wc * 96 + nj * 16 + r16]), 1e-12f);
#pragma unroll
    for (int mi = 0; mi < 3; mi++) {
#pragma unroll
        for (int r = 0; r < 4; r++) {
            int i = wr * 48 + mi * 16 + g * 4 + r;
            int ti = bench_idx[b * K_ + i];
            int hi = high[b * K_ + i];
            float invA = 1.0f / fmaxf(sqrtf(ssL[i]), 1e-12f);
            int y1 = ti / HW_, x1 = ti % HW_;
            unsigned short* prow = bwn + (size_t)(b * K_ + i) * N_;
            float sum6 = 0.f;
            float vals[6];
#pragma unroll
            for (int nj = 0; nj < 6; nj++) {
                int col = ct * 192 + wc * 96 + nj * 16 + r16;
                int y2 = col / HW_, x2 = col % HW_;
                float dy = (float)(y1 - y2), dx = (float)(x1 - x2);
                float dist = sqrtf(dy * dy + dx * dx);
                float pen = 1.0f - fminf(dist / DIST_THR_F, 1.0f);
                float v = fmaxf(acc[mi][nj][r], 0.0f) * invA * invB6[nj] * pen;
                vals[nj] = v;
                sum6 += v;
            }
            // reduce sum over the 16-lane r16 group
#pragma unroll
            for (int m = 1; m <= 8; m <<= 1) sum6 += __shfl_xor(sum6, m, 64);
            if (r16 == 0) atomicAdd(&rsum[i], sum6);
#pragma unroll
            for (int nj = 0; nj < 6; nj++) {
                int col = ct * 192 + wc * 96 + nj * 16 + r16;
                unsigned short o = (hi || col == ti) ? (unsigned short)0 : f2bf(vals[nj]);
                prow[col] = o;
            }
        }
    }
    __syncthreads();
    if (tid < 144) atomicAdd(&rowsum[b * K_ + tid], rsum[tid]);
}

// ---------------- Kernel 3: aggregation GEMM, fused transpose + normalize + self ----
// block = (b, dt in 0..3): 144 rows x 256 d-cols. 384 thr / 6 waves (3x2).
// out[i][d] = Y[i][d]/(S'[i]+1e-8) + agg[ti][d]  (Y excludes self; high rows Y=0)
__global__ __launch_bounds__(384) void k_agg5(const unsigned short* __restrict__ bwn,
                                              const float* __restrict__ agg,
                                              const int* __restrict__ bench_idx,
                                              const float* __restrict__ rowsum,
                                              float* __restrict__ out) {
    __shared__ unsigned short LA[144 * 64];
    __shared__ unsigned int   LB[256 * 32];     // [d][32 u32 of j-pairs]
    int bid  = blockIdx.x;
    int xcd  = bid & 7;
    int s    = bid >> 3;               // 0..31
    int dt   = s & 3;
    int b    = (s >> 2) * 8 + xcd;
    int tid  = threadIdx.x;
    int w = tid >> 6, lane = tid & 63, g = lane >> 4, r16 = lane & 15;
    int wr = w >> 1, wc = w & 1;       // rows wr*48, d-cols wc*128

    const unsigned short* asrc[3];
    int adso[3];
#pragma unroll
    for (int q = 0; q < 3; q++) {
        int cid = tid + 384 * q;
        int row = cid >> 3, p = cid & 7, l = p ^ (row & 7);
        asrc[q] = bwn + (size_t)(b * K_ + row) * N_ + l * 8;
        adso[q] = row * 64 + p * 8;
    }
    const float* bbase = agg + (size_t)b * N_ * D_ + dt * 256 + lane * 4;

    bf16x8 areg[3];
    float4 breg[6][2];
#pragma unroll
    for (int q = 0; q < 3; q++) areg[q] = *(const bf16x8*)(asrc[q]);
#pragma unroll
    for (int u = 0; u < 6; u++) {
        int pp = w + 6 * u;
        if (pp < 32) {
            breg[u][0] = *(const float4*)(bbase + (size_t)(2 * pp) * D_);
            breg[u][1] = *(const float4*)(bbase + (size_t)(2 * pp + 1) * D_);
        }
    }

    f32x4 acc[3][8] = {};

    for (int t = 0; t < 9; ++t) {
#pragma unroll
        for (int q = 0; q < 3; q++) *(bf16x8*)&LA[adso[q]] = areg[q];
#pragma unroll
        for (int u = 0; u < 6; u++) {
            int pp = w + 6 * u;
            if (pp < 32) {
                float a0[4] = { breg[u][0].x, breg[u][0].y, breg[u][0].z, breg[u][0].w };
                float a1[4] = { breg[u][1].x, breg[u][1].y, breg[u][1].z, breg[u][1].w };
                int js = pp >> 2;
#pragma unroll
                for (int c = 0; c < 4; c++) {
                    int d = lane * 4 + c;
                    int sw = (js ^ (d & 7) ^ ((d >> 3) & 7)) & 7;
                    unsigned pk = (unsigned)f2bf(a0[c]) | ((unsigned)f2bf(a1[c]) << 16);
                    LB[d * 32 + sw * 4 + (pp & 3)] = pk;
                }
            }
        }
        __syncthreads();
        if (t < 8) {
            int kb = (t + 1) * 64;
#pragma unroll
            for (int q = 0; q < 3; q++) areg[q] = *(const bf16x8*)(asrc[q] + kb);
#pragma unroll
            for (int u = 0; u < 6; u++) {
                int pp = w + 6 * u;
                if (pp < 32) {
                    breg[u][0] = *(const float4*)(bbase + (size_t)(kb + 2 * pp) * D_);
                    breg[u][1] = *(const float4*)(bbase + (size_t)(kb + 2 * pp + 1) * D_);
                }
            }
        }
#pragma unroll
        for (int h = 0; h < 2; h++) {
            int ks = h * 4 + g;
            bf16x8 af[3], bf[8];
#pragma unroll
            for (int mi = 0; mi < 3; mi++) {
                int row = wr * 48 + mi * 16 + r16;
                af[mi] = *(const bf16x8*)&LA[row * 64 + (ks ^ (row & 7)) * 8];
            }
#pragma unroll
            for (int nj = 0; nj < 8; nj++) {
                int d = wc * 128 + nj * 16 + r16;
                int sw = (ks ^ (d & 7) ^ ((d >> 3) & 7)) & 7;
                bf[nj] = *(const bf16x8*)&LB[d * 32 + sw * 4];
            }
#pragma unroll
            for (int mi = 0; mi < 3; mi++)
#pragma unroll
                for (int nj = 0; nj < 8; nj++)
                    acc[mi][nj] = __builtin_amdgcn_mfma_f32_16x16x32_bf16(af[mi], bf[nj], acc[mi][nj], 0, 0, 0);
        }
        __syncthreads();
    }

    // epilogue: normalize by S' and add self row (exact f32)
#pragma unroll
    for (int mi = 0; mi < 3; mi++) {
#pragma unroll
        for (int r = 0; r < 4; r++) {
            int i = wr * 48 + mi * 16 + g * 4 + r;
            float S = rowsum[b * K_ + i];
            float sc = 1.0f / (S + 1e-8f);
            int ti = bench_idx[b * K_ + i];
            const float* selfrow = agg + (size_t)(b * N_ + ti) * D_ + dt * 256 + wc * 128;
            float* orow = out + (size_t)(b * K_ + i) * D_ + dt * 256 + wc * 128;
#pragma unroll
            for (int nj = 0; nj < 8; nj++)
                orow[nj * 16 + r16] = acc[mi][nj][r] * sc + selfrow[nj * 16 + r16];
        }
    }
}

extern "C" void kernel_launch(void* const* d_in, const int* in_sizes, int n_in,
                              void* d_out, int out_size, void* d_ws, size_t ws_size,
                              hipStream_t stream) {
    const float* hs_agg = (const float*)d_in[0];
    const float* hs_sim = (const float*)d_in[1];
    const float* metric = (const float*)d_in[2];
    float* out = (float*)d_out;
    char* ws = (char*)d_ws;

    const size_t BWN_BYTES = (size_t)B_ * K_ * N_ * 2;    // 10,616,832
    unsigned short* bwn = (unsigned short*)ws;
    int*   bench_idx = (int*)(ws + BWN_BYTES);
    int*   high      = (int*)(ws + BWN_BYTES + (size_t)B_ * K_ * 4);
    float* rowsum    = (float*)(ws + BWN_BYTES + (size_t)B_ * K_ * 8);
    float* out_idx   = out + (size_t)B_ * K_ * D_;

    hipLaunchKernelGGL(k_select, dim3(B_),     dim3(256), 0, stream, metric, bench_idx, high, out_idx, rowsum);
    hipLaunchKernelGGL(k_sim5,   dim3(B_ * 3), dim3(384), 0, stream, hs_sim, bench_idx, high, bwn, rowsum);
    hipLaunchKernelGGL(k_agg5,   dim3(B_ * 4), dim3(384), 0, stream, bwn, hs_agg, bench_idx, rowsum, out);
}